// Round 8
// baseline (892.442 us; speedup 1.0000x reference)
//
#include <hip/hip_runtime.h>
#include <hip/hip_bf16.h>
#include <math.h>

using bf16 = __hip_bfloat16;
typedef __bf16 bf16x8 __attribute__((ext_vector_type(8)));
typedef __bf16 bf16x4 __attribute__((ext_vector_type(4)));
typedef float floatx4 __attribute__((ext_vector_type(4)));

__device__ __forceinline__ float bf2f(bf16 x) { return __bfloat162float(x); }
__device__ __forceinline__ bf16 f2bf(float x) { return __float2bfloat16(x); }

// flag semantics: flagp[0] == 1 -> external tensors are bf16; 0 -> float32.
__device__ __forceinline__ float loadExt(const void* p, long i, int f32) {
  return f32 ? ((const float*)p)[i] : bf2f(((const bf16*)p)[i]);
}
__device__ __forceinline__ void storeExt(void* p, long i, int f32, float v) {
  if (f32) ((float*)p)[i] = v;
  else     ((bf16*)p)[i] = f2bf(v);
}

// async 16B global->LDS copy (gfx950). LDS dest is wave-uniform base + lane*16.
#define GLOAD16(gp, lp)                                                       \
  __builtin_amdgcn_global_load_lds(                                           \
      (const __attribute__((address_space(1))) void*)(gp),                    \
      (__attribute__((address_space(3))) void*)(lp), 16, 0, 0)

// ---------------- dtype detector: 1 wave, inspects low 16 bits of 64 words ---
__global__ void detect_kernel(const unsigned int* __restrict__ q, int* __restrict__ flag) {
  const int lane = threadIdx.x;
  const unsigned int w = q[lane];
  const unsigned int lo = w & 0xffffu;
  const unsigned int e = (lo >> 7) & 0xffu;
  const bool ok = (lo == 0u) || (e >= 100u && e <= 141u);
  const unsigned long long m = __ballot(ok);
  if (lane == 0) flag[0] = (__popcll(m) == 64) ? 1 : 0;
}

// ---------------- combined 1-D param convert: 9 tensors -> contiguous bf16 ---
__global__ void cvt_params_kernel(const int* __restrict__ flagp,
                                  const void* qkv_b, const void* proj_b,
                                  const void* n1g, const void* n1b,
                                  const void* n2g, const void* n2b,
                                  const void* fc1_b, const void* fc2_b,
                                  const void* rpb, bf16* __restrict__ dst) {
  const int f32 = (flagp[0] == 0);
  int i = blockIdx.x * blockDim.x + threadIdx.x;
  if (i >= 3510) return;
  const void* src; int j = i;
  if      (j < 576)  { src = qkv_b; }
  else if ((j -= 576)  < 192) { src = proj_b; }
  else if ((j -= 192)  < 192) { src = n1g; }
  else if ((j -= 192)  < 192) { src = n1b; }
  else if ((j -= 192)  < 192) { src = n2g; }
  else if ((j -= 192)  < 192) { src = n2b; }
  else if ((j -= 192)  < 768) { src = fc1_b; }
  else if ((j -= 768)  < 192) { src = fc2_b; }
  else { j -= 192; src = rpb; }
  dst[i] = f2bf(loadExt(src, j, f32));
}

// ---------------- fused convert + transpose: src[K,N] (ext) -> dst[N,K] bf16 -
__global__ void cvtT_kernel(const int* __restrict__ flagp, const void* __restrict__ src,
                            bf16* __restrict__ dst, int K, int N) {
  const int f32 = (flagp[0] == 0);
  int i = blockIdx.x * blockDim.x + threadIdx.x;
  if (i >= K * N) return;
  int n = i / K, k = i - n * K;
  dst[i] = f2bf(loadExt(src, (long)k * N + n, f32));
}

// ---------------- rel-pos bias table: btab[head][n*50+m] (padded stride 50) --
__global__ void biastab_kernel(const bf16* __restrict__ rpb,
                               bf16* __restrict__ btab) {
  int i = blockIdx.x * blockDim.x + threadIdx.x;
  if (i >= 6 * 2450) return;
  int head = i / 2450, r = i - head * 2450;
  int n = r / 50, m = r - n * 50;
  float v = 0.f;
  if (n < 49 && m < 49) {
    int r1 = n / 7, c1 = n - 7 * r1, r2 = m / 7, c2 = m - 7 * r2;
    v = bf2f(rpb[((r1 - r2 + 6) * 13 + (c1 - c2 + 6)) * 6 + head]);
  }
  btab[i] = f2bf(v);
}

// ---------------- LayerNorm: one wave per 192-elem row --------------------
__global__ __launch_bounds__(256) void ln_kernel(const int* __restrict__ flagp, int ext,
                                                 const void* __restrict__ x,
                                                 const bf16* __restrict__ g,
                                                 const bf16* __restrict__ b,
                                                 bf16* __restrict__ out) {
  const int f32 = ext && (flagp[0] == 0);
  const long row = (long)blockIdx.x * 4 + (threadIdx.x >> 6);
  const int lane = threadIdx.x & 63;
  const long gbase = row * 192;
  float v0 = loadExt(x, gbase + lane, f32);
  float v1 = loadExt(x, gbase + lane + 64, f32);
  float v2 = loadExt(x, gbase + lane + 128, f32);
  float s = v0 + v1 + v2;
  #pragma unroll
  for (int off = 32; off > 0; off >>= 1) s += __shfl_xor(s, off, 64);
  const float mu = s * (1.0f / 192.0f);
  float d0 = v0 - mu, d1 = v1 - mu, d2 = v2 - mu;
  float vv = d0 * d0 + d1 * d1 + d2 * d2;
  #pragma unroll
  for (int off = 32; off > 0; off >>= 1) vv += __shfl_xor(vv, off, 64);
  const float rstd = rsqrtf(vv * (1.0f / 192.0f) + 1e-5f);
  bf16* orow = out + row * 192;
  orow[lane]       = f2bf(d0 * rstd * bf2f(g[lane])       + bf2f(b[lane]));
  orow[lane + 64]  = f2bf(d1 * rstd * bf2f(g[lane + 64])  + bf2f(b[lane + 64]));
  orow[lane + 128] = f2bf(d2 * rstd * bf2f(g[lane + 128]) + bf2f(b[lane + 128]));
}

// ---------------- bf16 MFMA GEMM (round-4 structure): 2-buffer prefetch ----
// EPI: 0 = bias, 1 = bias+GELU(exact), 2 = bias+residual.
template <int EPI>
__global__ __launch_bounds__(256) void gemm_bt(const bf16* __restrict__ A,
                                               const bf16* __restrict__ BT,
                                               const bf16* __restrict__ bias,
                                               const int* __restrict__ flagp,
                                               const void* res, int res_ext,
                                               void* out, int out_ext,
                                               int M, int N, int K) {
  __shared__ __align__(16) bf16 As[2][128 * 32];
  __shared__ __align__(16) bf16 Bs[2][64 * 32];
  const int xf32 = (flagp[0] == 0);
  const int tid = threadIdx.x;
  const int wave = tid >> 6;
  const int lane = tid & 63;
  const int l16 = lane & 15;
  const int quad = lane >> 4;

  const int nbn = N >> 6;
  const int cpx = gridDim.x >> 3;
  const int wg = (gridDim.x & 7) ? (int)blockIdx.x
                                 : (blockIdx.x & 7) * cpx + (blockIdx.x >> 3);
  const int mb = wg / nbn;
  const int nb = wg - mb * nbn;
  const long m0 = (long)mb * 128;
  const int n0 = nb << 6;

  const int rS = tid >> 2;
  const int sS = tid & 3;
  const int ss = sS ^ ((rS >> 1) & 3);
  const bf16* gA0 = A + (m0 + rS) * (long)K + ss * 8;
  const bf16* gA1 = A + (m0 + rS + 64) * (long)K + ss * 8;
  const bf16* gB  = BT + (long)(n0 + rS) * K + ss * 8;

  floatx4 acc[2][4];
  #pragma unroll
  for (int i = 0; i < 2; i++)
    #pragma unroll
    for (int j = 0; j < 4; j++) acc[i][j] = (floatx4){0.f, 0.f, 0.f, 0.f};

  const int swz = (quad ^ ((l16 >> 1) & 3)) << 3;
  const int arow = wave * 32 + l16;

  GLOAD16(gA0, &As[0][tid * 8]);
  GLOAD16(gA1, &As[0][(tid + 256) * 8]);
  GLOAD16(gB,  &Bs[0][tid * 8]);
  __syncthreads();

  int cur = 0;
  for (int k0 = 0; k0 < K; k0 += 32) {
    if (k0 + 32 < K) {
      const int nxt = cur ^ 1;
      GLOAD16(gA0 + k0 + 32, &As[nxt][tid * 8]);
      GLOAD16(gA1 + k0 + 32, &As[nxt][(tid + 256) * 8]);
      GLOAD16(gB  + k0 + 32, &Bs[nxt][tid * 8]);
    }
    bf16x8 af[2], bfr[4];
    #pragma unroll
    for (int ms = 0; ms < 2; ms++)
      af[ms] = *(const bf16x8*)&As[cur][(arow + ms * 16) * 32 + swz];
    #pragma unroll
    for (int ns = 0; ns < 4; ns++)
      bfr[ns] = *(const bf16x8*)&Bs[cur][(ns * 16 + l16) * 32 + swz];
    #pragma unroll
    for (int ms = 0; ms < 2; ms++)
      #pragma unroll
      for (int ns = 0; ns < 4; ns++)
        acc[ms][ns] = __builtin_amdgcn_mfma_f32_16x16x32_bf16(bfr[ns], af[ms], acc[ms][ns], 0, 0, 0);
    __syncthreads();
    cur ^= 1;
  }

  #pragma unroll
  for (int ms = 0; ms < 2; ms++) {
    const long row = m0 + wave * 32 + ms * 16 + l16;
    #pragma unroll
    for (int ns = 0; ns < 4; ns++) {
      const int col = n0 + ns * 16 + quad * 4;
      const long idx = row * (long)N + col;
      float v[4];
      #pragma unroll
      for (int r = 0; r < 4; r++) v[r] = acc[ms][ns][r] + bf2f(bias[col + r]);
      if (EPI == 1) {
        #pragma unroll
        for (int r = 0; r < 4; r++)
          v[r] = 0.5f * v[r] * (1.0f + erff(v[r] * 0.70710678118654752f));
      }
      if (EPI == 2) {
        if (res_ext && xf32) {
          const float4 t = *(const float4*)((const float*)res + idx);
          v[0] += t.x; v[1] += t.y; v[2] += t.z; v[3] += t.w;
        } else {
          const bf16x4 t = *(const bf16x4*)((const bf16*)res + idx);
          #pragma unroll
          for (int r = 0; r < 4; r++) v[r] += (float)t[r];
        }
      }
      if (out_ext && xf32) {
        float4 t; t.x = v[0]; t.y = v[1]; t.z = v[2]; t.w = v[3];
        *(float4*)((float*)out + idx) = t;
      } else {
        bf16x4 t;
        #pragma unroll
        for (int r = 0; r < 4; r++) t[r] = (__bf16)v[r];
        *(bf16x4*)((bf16*)out + idx) = t;
      }
    }
  }
}

// ---------------- fused LN2 + FC1 + GELU + FC2 + residual (v3) --------------
// Occupancy-first redesign: 4 waves x 16 rows = 64-row panel, 1568 blocks.
// Per-wave regs: C[12]=48 + h[4]=16 + afr[6]=24 + temps -> ~160 total;
// __launch_bounds__(256,3) caps at 170 -> 3 waves/SIMD (12 waves/CU).
// LDS 24 KB, phase-aliased: Ash[64][192] (stage+LN) -> H dbuf 2x[64][72]
// (pad +8 breaks the 128B-stride bank degeneracy; H traffic is tiny anyway:
// 8x8B writes + 2x16B reads per wave per slice, waves own their rows ->
// NO barriers in the slice loop). W1/W2 fragments direct from global:
// identical across the block's 4 waves (L1 hits) and shared by ~196
// blocks/XCD (L2-resident, 576 KB); barrier-free loop lets the compiler
// hoist all fragment loads ahead of the MFMA chain.
__global__ __launch_bounds__(256, 3) void mlp_fused(
    const bf16* __restrict__ xb,   // [M,192] residual (pre-LN), bf16
    const bf16* __restrict__ w1,   // fc1T [768][192]
    const bf16* __restrict__ w2,   // fc2T [192][768]
    const bf16* __restrict__ gN, const bf16* __restrict__ bN,
    const bf16* __restrict__ b1, const bf16* __restrict__ b2,
    const int* __restrict__ flagp, void* __restrict__ out) {
  __shared__ __align__(16) char smem[24576];   // 24 KB, phase-aliased
  __bf16* Ash = (__bf16*)smem;                 // [64][192] staging / LN out
  __bf16* Hb  = (__bf16*)smem;                 // [2][64][72] h dbuf (18 KB)
  const int xf32 = (flagp[0] == 0);
  const int tid = threadIdx.x, wave = tid >> 6, lane = tid & 63;
  const int l16 = lane & 15, quad = lane >> 4;
  const int cpx = gridDim.x >> 3;
  const int mb = (gridDim.x & 7) ? (int)blockIdx.x
                                 : (int)(blockIdx.x & 7) * cpx + (int)(blockIdx.x >> 3);
  const long m0 = (long)mb * 64;

  // ---- stage raw xbuf panel (64 x 192), linear ----
  {
    const bf16* src = xb + m0 * 192;
    #pragma unroll
    for (int i = 0; i < 6; i++)
      GLOAD16(src + (i * 256 + tid) * 8, &Ash[(i * 256 + tid) * 8]);
  }
  asm volatile("s_waitcnt vmcnt(0)" ::: "memory");
  __builtin_amdgcn_s_barrier();

  // ---- LN2: 4 threads per row, 6 slots (48 elems) each ----
  {
    const int row = tid >> 2, part = tid & 3;
    bf16x8 xr[6];
    #pragma unroll
    for (int i = 0; i < 6; i++)
      xr[i] = *(const bf16x8*)&Ash[row * 192 + (part * 6 + i) * 8];
    float s1 = 0.f;
    #pragma unroll
    for (int i = 0; i < 6; i++)
      #pragma unroll
      for (int j = 0; j < 8; j++) s1 += (float)xr[i][j];
    s1 += __shfl_xor(s1, 1, 64);
    s1 += __shfl_xor(s1, 2, 64);
    const float mu = s1 * (1.0f / 192.0f);
    float s2 = 0.f;
    #pragma unroll
    for (int i = 0; i < 6; i++)
      #pragma unroll
      for (int j = 0; j < 8; j++) {
        const float d = (float)xr[i][j] - mu;
        s2 += d * d;
      }
    s2 += __shfl_xor(s2, 1, 64);
    s2 += __shfl_xor(s2, 2, 64);
    const float rstd = rsqrtf(s2 * (1.0f / 192.0f) + 1e-5f);
    #pragma unroll
    for (int i = 0; i < 6; i++) {
      const int slot = part * 6 + i;
      const bf16x8 gg = *(const bf16x8*)&gN[slot * 8];
      const bf16x8 bb = *(const bf16x8*)&bN[slot * 8];
      bf16x8 nr;
      #pragma unroll
      for (int j = 0; j < 8; j++)
        nr[j] = (__bf16)(((float)xr[i][j] - mu) * rstd * (float)gg[j] + (float)bb[j]);
      xr[i] = nr;
    }
    __syncthreads();                 // all raw reads done before permuted writes
    #pragma unroll
    for (int i = 0; i < 6; i++) {
      const int slot = part * 6 + i;
      const int sw = (slot & 24) | ((slot ^ row) & 7);
      *(bf16x8*)&Ash[row * 192 + sw * 8] = xr[i];
    }
  }
  __syncthreads();

  // ---- hoist A fragments to registers (slice-invariant); rows wave*16+l16 --
  bf16x8 afr[6];
  {
    const int r = wave * 16 + l16;
    #pragma unroll
    for (int ks = 0; ks < 6; ks++) {
      const int sl = ks * 4 + quad;
      afr[ks] = *(const bf16x8*)&Ash[r * 192 + ((sl & 24) | ((sl ^ r) & 7)) * 8];
    }
  }
  __syncthreads();                   // release Ash region for H reuse

  floatx4 C[12];
  #pragma unroll
  for (int nt = 0; nt < 12; nt++) C[nt] = (floatx4){0.f, 0.f, 0.f, 0.f};

  const int m = wave * 16 + l16;     // this lane's owned row (local)

  for (int s = 0; s < 12; ++s) {
    __bf16* H = Hb + (s & 1) * (64 * 72);
    // mma1: h = W1s x A  (D[j on quad*4+r][m on l16]); W1 frags direct global
    floatx4 h[4];
    #pragma unroll
    for (int jt = 0; jt < 4; jt++) h[jt] = (floatx4){0.f, 0.f, 0.f, 0.f};
    #pragma unroll
    for (int ks = 0; ks < 6; ks++) {
      bf16x8 wf[4];
      #pragma unroll
      for (int jt = 0; jt < 4; jt++)
        wf[jt] = *(const bf16x8*)&w1[(long)(s * 64 + jt * 16 + l16) * 192 + ks * 32 + quad * 8];
      #pragma unroll
      for (int jt = 0; jt < 4; jt++)
        h[jt] = __builtin_amdgcn_mfma_f32_16x16x32_bf16(wf[jt], afr[ks], h[jt], 0, 0, 0);
    }
    // bias + GELU -> H (8B packed, padded row 72; rows private to wave)
    #pragma unroll
    for (int jt = 0; jt < 4; jt++) {
      bf16x4 pk;
      #pragma unroll
      for (int r = 0; r < 4; r++) {
        const int j = jt * 16 + quad * 4 + r;
        float v = h[jt][r] + bf2f(b1[s * 64 + j]);
        v = 0.5f * v * (1.0f + erff(v * 0.70710678118654752f));
        pk[r] = (__bf16)v;
      }
      *(bf16x4*)&H[m * 72 + (jt * 4 + quad) * 4] = pk;
    }
    // mma2: C += W2s x h  (D[n on quad*4+r][m on l16]); W2 frags direct global
    #pragma unroll
    for (int k2 = 0; k2 < 2; k2++) {
      const bf16x8 hf = *(const bf16x8*)&H[m * 72 + k2 * 32 + quad * 8];
      #pragma unroll
      for (int nt = 0; nt < 12; nt++) {
        const bf16x8 wf2 = *(const bf16x8*)&w2[(long)(nt * 16 + l16) * 768 + s * 64 + k2 * 32 + quad * 8];
        C[nt] = __builtin_amdgcn_mfma_f32_16x16x32_bf16(wf2, hf, C[nt], 0, 0, 0);
      }
    }
  }

  // ---- epilogue: out = xb + C + b2 ----
  {
    const long row = m0 + wave * 16 + l16;
    #pragma unroll
    for (int nt = 0; nt < 12; nt++) {
      const int col = nt * 16 + quad * 4;
      const long idx = row * 192 + col;
      float v[4];
      #pragma unroll
      for (int r = 0; r < 4; r++) v[r] = C[nt][r] + bf2f(b2[col + r]);
      const bf16x4 t = *(const bf16x4*)&xb[idx];
      #pragma unroll
      for (int r = 0; r < 4; r++) v[r] += (float)t[r];
      if (xf32) {
        float4 o; o.x = v[0]; o.y = v[1]; o.z = v[2]; o.w = v[3];
        *(float4*)((float*)out + idx) = o;
      } else {
        bf16x4 o;
        #pragma unroll
        for (int r = 0; r < 4; r++) o[r] = (__bf16)v[r];
        *(bf16x4*)((bf16*)out + idx) = o;
      }
    }
  }
}

// ---------------- MFMA window attention: one wave per (window, head) --------
__global__ __launch_bounds__(64, 3) void attn_kernel(const bf16* __restrict__ qkv,  // [100352,576]
                                                     const bf16* __restrict__ btab, // [6,2450]
                                                     bf16* __restrict__ out) {      // [100352,192]
  __shared__ __align__(16) __bf16 vshT[32 * 64];  // V^T: [d][j], swizzled
  __shared__ __align__(16) __bf16 psh[64 * 64];   // P:   [i][j], swizzled
  __shared__ int rowIdx[64];
  __shared__ int regn[64];
  const int lane = threadIdx.x;
  const int q = lane >> 4, l16 = lane & 15;
  const int unit = blockIdx.x;          // [0, 12288)
  const int head = unit % 6;
  const int wIdx = unit / 6;            // [0, 2048)
  const int b = wIdx >> 8;
  const int w2 = wIdx & 255;
  const int wh = w2 >> 4;
  const int ww = w2 & 15;

  {
    const int l = lane < 49 ? lane : 48;
    const int r = l / 7, c = l - 7 * r;
    const int hr = wh * 7 + r;
    const int wr = ww * 7 + c;
    int h = hr + 3; if (h >= 112) h -= 112;
    int w = wr + 3; if (w >= 112) w -= 112;
    rowIdx[lane] = b * 12544 + h * 112 + w;
    const int rh = hr < 105 ? 0 : (hr < 109 ? 1 : 2);
    const int rw = wr < 105 ? 0 : (wr < 109 ? 1 : 2);
    regn[lane] = (lane < 49) ? rh * 3 + rw : 99;
  }
  __syncthreads();

  int ridx[4];
  #pragma unroll
  for (int t = 0; t < 4; t++) ridx[t] = rowIdx[t * 16 + l16];

  #pragma unroll
  for (int ii = 0; ii < 4; ii++) {
    const int i = lane + ii * 64;
    const int j = i >> 2, c = (i & 3) * 8;
    const bf16x8 vv = *(const bf16x8*)&qkv[(long)rowIdx[j] * 576 + 384 + head * 32 + c];
    #pragma unroll
    for (int jj = 0; jj < 8; jj++) {
      const int d = c + jj;
      vshT[d * 64 + (((j >> 3) ^ (d & 7)) << 3) + (j & 7)] = vv[jj];
    }
  }

  floatx4 s[4][4];
  #pragma unroll
  for (int it = 0; it < 4; it++)
    #pragma unroll
    for (int jt = 0; jt < 4; jt++) s[it][jt] = (floatx4){0.f, 0.f, 0.f, 0.f};
  {
    bf16x8 afq[4], bfk[4];
    #pragma unroll
    for (int t = 0; t < 4; t++) {
      const bf16* pQ = &qkv[(long)ridx[t] * 576 + head * 32 + q * 8];
      afq[t] = *(const bf16x8*)pQ;
      bfk[t] = *(const bf16x8*)(pQ + 192);
    }
    #pragma unroll
    for (int it = 0; it < 4; it++)
      #pragma unroll
      for (int jt = 0; jt < 4; jt++)
        s[it][jt] = __builtin_amdgcn_mfma_f32_16x16x32_bf16(afq[it], bfk[jt], s[it][jt], 0, 0, 0);
  }

  int regj[4];
  #pragma unroll
  for (int jt = 0; jt < 4; jt++) regj[jt] = regn[jt * 16 + l16];
  int regi[4][4];
  #pragma unroll
  for (int it = 0; it < 4; it++)
    #pragma unroll
    for (int r = 0; r < 4; r++) regi[it][r] = regn[it * 16 + q * 4 + r];

  const bf16* bt = btab + head * 2450;
  const float scale = 0.17677669529663687f;
  float mrow[4][4];
  #pragma unroll
  for (int it = 0; it < 4; it++)
    #pragma unroll
    for (int r = 0; r < 4; r++) mrow[it][r] = -3e38f;

  #pragma unroll
  for (int it = 0; it < 4; it++)
    #pragma unroll
    for (int jt = 0; jt < 4; jt++)
      #pragma unroll
      for (int r = 0; r < 4; r++) {
        const int i = it * 16 + q * 4 + r;
        const int j = jt * 16 + l16;
        const int bi = (i < 49 ? i : 48) * 50 + (j < 49 ? j : 48);
        float v = s[it][jt][r] * scale + bf2f(bt[bi]);
        if (regi[it][r] != regj[jt]) v -= 100.0f;
        v = (j < 49) ? v : -1e30f;
        s[it][jt][r] = v;
        mrow[it][r] = fmaxf(mrow[it][r], v);
      }
  #pragma unroll
  for (int it = 0; it < 4; it++)
    #pragma unroll
    for (int r = 0; r < 4; r++) {
      float m = mrow[it][r];
      #pragma unroll
      for (int off = 1; off < 16; off <<= 1) m = fmaxf(m, __shfl_xor(m, off, 64));
      mrow[it][r] = m;
    }
  float sum[4][4];
  #pragma unroll
  for (int it = 0; it < 4; it++)
    #pragma unroll
    for (int r = 0; r < 4; r++) sum[it][r] = 0.f;
  #pragma unroll
  for (int it = 0; it < 4; it++)
    #pragma unroll
    for (int jt = 0; jt < 4; jt++)
      #pragma unroll
      for (int r = 0; r < 4; r++) {
        const float e = __expf(s[it][jt][r] - mrow[it][r]);
        s[it][jt][r] = e;
        sum[it][r] += e;
      }
  #pragma unroll
  for (int it = 0; it < 4; it++)
    #pragma unroll
    for (int r = 0; r < 4; r++) {
      float t = sum[it][r];
      #pragma unroll
      for (int off = 1; off < 16; off <<= 1) t += __shfl_xor(t, off, 64);
      mrow[it][r] = 1.0f / t;
    }

  #pragma unroll
  for (int it = 0; it < 4; it++)
    #pragma unroll
    for (int jt = 0; jt < 4; jt++)
      #pragma unroll
      for (int r = 0; r < 4; r++) {
        const int i = it * 16 + q * 4 + r;
        const int j = jt * 16 + l16;
        psh[i * 64 + (((j >> 3) ^ (i & 7)) << 3) + (j & 7)] =
            (__bf16)(s[it][jt][r] * mrow[it][r]);
      }
  __syncthreads();

  floatx4 o[4][2];
  #pragma unroll
  for (int it = 0; it < 4; it++)
    #pragma unroll
    for (int dt = 0; dt < 2; dt++) o[it][dt] = (floatx4){0.f, 0.f, 0.f, 0.f};
  #pragma unroll
  for (int ks = 0; ks < 2; ks++) {
    bf16x8 av[2];
    #pragma unroll
    for (int dt = 0; dt < 2; dt++) {
      const int row = dt * 16 + l16;
      av[dt] = *(const bf16x8*)&vshT[row * 64 + (((ks * 4 + q) ^ (row & 7)) << 3)];
    }
    #pragma unroll
    for (int it = 0; it < 4; it++) {
      const int row = it * 16 + l16;
      const bf16x8 bp = *(const bf16x8*)&psh[row * 64 + (((ks * 4 + q) ^ (row & 7)) << 3)];
      #pragma unroll
      for (int dt = 0; dt < 2; dt++)
        o[it][dt] = __builtin_amdgcn_mfma_f32_16x16x32_bf16(bp, av[dt], o[it][dt], 0, 0, 0);
    }
  }

  #pragma unroll
  for (int it = 0; it < 4; it++)
    #pragma unroll
    for (int r = 0; r < 4; r++) {
      const int i = it * 16 + q * 4 + r;
      if (i < 49) {
        const long ob = (long)rowIdx[i] * 192 + head * 32;
        #pragma unroll
        for (int dt = 0; dt < 2; dt++)
          out[ob + dt * 16 + l16] = f2bf(o[it][dt][r]);
      }
    }
}

// ---------------------------------------------------------------------------
extern "C" void kernel_launch(void* const* d_in, const int* in_sizes, int n_in,
                              void* d_out, int out_size, void* d_ws, size_t ws_size,
                              hipStream_t stream) {
  const void* query   = d_in[0];
  const void* norm1_g = d_in[1];
  const void* norm1_b = d_in[2];
  const void* qkv_w   = d_in[3];
  const void* qkv_b   = d_in[4];
  const void* rpb     = d_in[5];
  const void* proj_w  = d_in[6];
  const void* proj_b  = d_in[7];
  const void* norm2_g = d_in[8];
  const void* norm2_b = d_in[9];
  const void* fc1_w   = d_in[10];
  const void* fc1_b   = d_in[11];
  const void* fc2_w   = d_in[12];
  const void* fc2_b   = d_in[13];

  const long M = 100352;

  int* flag  = (int*)d_ws;
  bf16* base = (bf16*)((char*)d_ws + 16);
  bf16* wsA   = base;                   // 19,267,584
  bf16* wsB   = wsA + M * 192;          // 77,070,336
  bf16* xbuf  = wsB + M * 768;          // 19,267,584
  bf16* qkvT  = xbuf + M * 192;         // 110,592
  bf16* projT = qkvT + 110592;          // 36,864
  bf16* fc1T  = projT + 36864;          // 147,456
  bf16* fc2T  = fc1T + 147456;          // 147,456
  bf16* pPAR  = fc2T + 147456;          // 3,510
  bf16* pQKVB = pPAR;                   // 576
  bf16* pPRJB = pQKVB + 576;            // 192
  bf16* pN1G  = pPRJB + 192;
  bf16* pN1B  = pN1G + 192;
  bf16* pN2G  = pN1B + 192;
  bf16* pN2B  = pN2G + 192;
  bf16* pFC1B = pN2B + 192;             // 768
  bf16* pFC2B = pFC1B + 768;            // 192
  bf16* pRPB  = pFC2B + 192;            // 1,014
  bf16* btab  = pPAR + 3510;            // 14,700

  detect_kernel<<<1, 64, 0, stream>>>((const unsigned int*)query, flag);
  cvt_params_kernel<<<14, 256, 0, stream>>>(flag, qkv_b, proj_b, norm1_g, norm1_b,
                                            norm2_g, norm2_b, fc1_b, fc2_b, rpb, pPAR);
  cvtT_kernel<<<(192 * 576 + 255) / 256, 256, 0, stream>>>(flag, qkv_w, qkvT, 192, 576);
  cvtT_kernel<<<(192 * 192 + 255) / 256, 256, 0, stream>>>(flag, proj_w, projT, 192, 192);
  cvtT_kernel<<<(192 * 768 + 255) / 256, 256, 0, stream>>>(flag, fc1_w, fc1T, 192, 768);
  cvtT_kernel<<<(768 * 192 + 255) / 256, 256, 0, stream>>>(flag, fc2_w, fc2T, 768, 192);
  biastab_kernel<<<(6 * 2450 + 255) / 256, 256, 0, stream>>>(pRPB, btab);

  // ---- attention branch ----
  ln_kernel<<<M / 4, 256, 0, stream>>>(flag, 1, query, pN1G, pN1B, wsA);
  gemm_bt<0><<<784 * 9, 256, 0, stream>>>(wsA, qkvT, pQKVB, flag,
                                          nullptr, 0, wsB, 0, (int)M, 576, 192);
  attn_kernel<<<12288, 64, 0, stream>>>(wsB, btab, wsA);
  // x = query + attn @ proj_w + b -> xbuf (bf16 internal)
  gemm_bt<2><<<784 * 3, 256, 0, stream>>>(wsA, projT, pPRJB, flag,
                                          query, 1, xbuf, 0, (int)M, 192, 192);

  // ---- fused MLP branch: out = xbuf + GELU(LN2(xbuf)@fc1)@fc2 ----
  mlp_fused<<<1568, 256, 0, stream>>>(xbuf, fc1T, fc2T, pN2G, pN2B,
                                      pFC1B, pFC2B, flag, d_out);
}

// Round 9
// 617.291 us; speedup vs baseline: 1.4457x; 1.4457x over previous
//
#include <hip/hip_runtime.h>
#include <hip/hip_bf16.h>
#include <math.h>

using bf16 = __hip_bfloat16;
typedef __bf16 bf16x8 __attribute__((ext_vector_type(8)));
typedef __bf16 bf16x4 __attribute__((ext_vector_type(4)));
typedef float floatx4 __attribute__((ext_vector_type(4)));

__device__ __forceinline__ float bf2f(bf16 x) { return __bfloat162float(x); }
__device__ __forceinline__ bf16 f2bf(float x) { return __float2bfloat16(x); }

// flag semantics: flagp[0] == 1 -> external tensors are bf16; 0 -> float32.
__device__ __forceinline__ float loadExt(const void* p, long i, int f32) {
  return f32 ? ((const float*)p)[i] : bf2f(((const bf16*)p)[i]);
}
__device__ __forceinline__ void storeExt(void* p, long i, int f32, float v) {
  if (f32) ((float*)p)[i] = v;
  else     ((bf16*)p)[i] = f2bf(v);
}

// async 16B global->LDS copy (gfx950). LDS dest is wave-uniform base + lane*16.
#define GLOAD16(gp, lp)                                                       \
  __builtin_amdgcn_global_load_lds(                                           \
      (const __attribute__((address_space(1))) void*)(gp),                    \
      (__attribute__((address_space(3))) void*)(lp), 16, 0, 0)

// ---------------- dtype detector: 1 wave, inspects low 16 bits of 64 words ---
__global__ void detect_kernel(const unsigned int* __restrict__ q, int* __restrict__ flag) {
  const int lane = threadIdx.x;
  const unsigned int w = q[lane];
  const unsigned int lo = w & 0xffffu;
  const unsigned int e = (lo >> 7) & 0xffu;
  const bool ok = (lo == 0u) || (e >= 100u && e <= 141u);
  const unsigned long long m = __ballot(ok);
  if (lane == 0) flag[0] = (__popcll(m) == 64) ? 1 : 0;
}

// ---------------- combined 1-D param convert: 9 tensors -> contiguous bf16 ---
__global__ void cvt_params_kernel(const int* __restrict__ flagp,
                                  const void* qkv_b, const void* proj_b,
                                  const void* n1g, const void* n1b,
                                  const void* n2g, const void* n2b,
                                  const void* fc1_b, const void* fc2_b,
                                  const void* rpb, bf16* __restrict__ dst) {
  const int f32 = (flagp[0] == 0);
  int i = blockIdx.x * blockDim.x + threadIdx.x;
  if (i >= 3510) return;
  const void* src; int j = i;
  if      (j < 576)  { src = qkv_b; }
  else if ((j -= 576)  < 192) { src = proj_b; }
  else if ((j -= 192)  < 192) { src = n1g; }
  else if ((j -= 192)  < 192) { src = n1b; }
  else if ((j -= 192)  < 192) { src = n2g; }
  else if ((j -= 192)  < 192) { src = n2b; }
  else if ((j -= 192)  < 768) { src = fc1_b; }
  else if ((j -= 768)  < 192) { src = fc2_b; }
  else { j -= 192; src = rpb; }
  dst[i] = f2bf(loadExt(src, j, f32));
}

// ---------------- fused convert + transpose: src[K,N] (ext) -> dst[N,K] bf16 -
__global__ void cvtT_kernel(const int* __restrict__ flagp, const void* __restrict__ src,
                            bf16* __restrict__ dst, int K, int N) {
  const int f32 = (flagp[0] == 0);
  int i = blockIdx.x * blockDim.x + threadIdx.x;
  if (i >= K * N) return;
  int n = i / K, k = i - n * K;
  dst[i] = f2bf(loadExt(src, (long)k * N + n, f32));
}

// ---------------- rel-pos bias table: btab[head][n*50+m] (padded stride 50) --
__global__ void biastab_kernel(const bf16* __restrict__ rpb,
                               bf16* __restrict__ btab) {
  int i = blockIdx.x * blockDim.x + threadIdx.x;
  if (i >= 6 * 2450) return;
  int head = i / 2450, r = i - head * 2450;
  int n = r / 50, m = r - n * 50;
  float v = 0.f;
  if (n < 49 && m < 49) {
    int r1 = n / 7, c1 = n - 7 * r1, r2 = m / 7, c2 = m - 7 * r2;
    v = bf2f(rpb[((r1 - r2 + 6) * 13 + (c1 - c2 + 6)) * 6 + head]);
  }
  btab[i] = f2bf(v);
}

// ---------------- LayerNorm: one wave per 192-elem row --------------------
__global__ __launch_bounds__(256) void ln_kernel(const int* __restrict__ flagp, int ext,
                                                 const void* __restrict__ x,
                                                 const bf16* __restrict__ g,
                                                 const bf16* __restrict__ b,
                                                 bf16* __restrict__ out) {
  const int f32 = ext && (flagp[0] == 0);
  const long row = (long)blockIdx.x * 4 + (threadIdx.x >> 6);
  const int lane = threadIdx.x & 63;
  const long gbase = row * 192;
  float v0 = loadExt(x, gbase + lane, f32);
  float v1 = loadExt(x, gbase + lane + 64, f32);
  float v2 = loadExt(x, gbase + lane + 128, f32);
  float s = v0 + v1 + v2;
  #pragma unroll
  for (int off = 32; off > 0; off >>= 1) s += __shfl_xor(s, off, 64);
  const float mu = s * (1.0f / 192.0f);
  float d0 = v0 - mu, d1 = v1 - mu, d2 = v2 - mu;
  float vv = d0 * d0 + d1 * d1 + d2 * d2;
  #pragma unroll
  for (int off = 32; off > 0; off >>= 1) vv += __shfl_xor(vv, off, 64);
  const float rstd = rsqrtf(vv * (1.0f / 192.0f) + 1e-5f);
  bf16* orow = out + row * 192;
  orow[lane]       = f2bf(d0 * rstd * bf2f(g[lane])       + bf2f(b[lane]));
  orow[lane + 64]  = f2bf(d1 * rstd * bf2f(g[lane + 64])  + bf2f(b[lane + 64]));
  orow[lane + 128] = f2bf(d2 * rstd * bf2f(g[lane + 128]) + bf2f(b[lane + 128]));
}

// ---------------- bf16 MFMA GEMM (round-4 proven): 2-buffer prefetch --------
// EPI: 0 = bias, 1 = bias+GELU(exact), 2 = bias+residual.  (used for fc2)
template <int EPI>
__global__ __launch_bounds__(256) void gemm_bt(const bf16* __restrict__ A,
                                               const bf16* __restrict__ BT,
                                               const bf16* __restrict__ bias,
                                               const int* __restrict__ flagp,
                                               const void* res, int res_ext,
                                               void* out, int out_ext,
                                               int M, int N, int K) {
  __shared__ __align__(16) bf16 As[2][128 * 32];
  __shared__ __align__(16) bf16 Bs[2][64 * 32];
  const int xf32 = (flagp[0] == 0);
  const int tid = threadIdx.x;
  const int wave = tid >> 6;
  const int lane = tid & 63;
  const int l16 = lane & 15;
  const int quad = lane >> 4;

  const int nbn = N >> 6;
  const int cpx = gridDim.x >> 3;
  const int wg = (gridDim.x & 7) ? (int)blockIdx.x
                                 : (blockIdx.x & 7) * cpx + (blockIdx.x >> 3);
  const int mb = wg / nbn;
  const int nb = wg - mb * nbn;
  const long m0 = (long)mb * 128;
  const int n0 = nb << 6;

  const int rS = tid >> 2;
  const int sS = tid & 3;
  const int ss = sS ^ ((rS >> 1) & 3);
  const bf16* gA0 = A + (m0 + rS) * (long)K + ss * 8;
  const bf16* gA1 = A + (m0 + rS + 64) * (long)K + ss * 8;
  const bf16* gB  = BT + (long)(n0 + rS) * K + ss * 8;

  floatx4 acc[2][4];
  #pragma unroll
  for (int i = 0; i < 2; i++)
    #pragma unroll
    for (int j = 0; j < 4; j++) acc[i][j] = (floatx4){0.f, 0.f, 0.f, 0.f};

  const int swz = (quad ^ ((l16 >> 1) & 3)) << 3;
  const int arow = wave * 32 + l16;

  GLOAD16(gA0, &As[0][tid * 8]);
  GLOAD16(gA1, &As[0][(tid + 256) * 8]);
  GLOAD16(gB,  &Bs[0][tid * 8]);
  __syncthreads();

  int cur = 0;
  for (int k0 = 0; k0 < K; k0 += 32) {
    if (k0 + 32 < K) {
      const int nxt = cur ^ 1;
      GLOAD16(gA0 + k0 + 32, &As[nxt][tid * 8]);
      GLOAD16(gA1 + k0 + 32, &As[nxt][(tid + 256) * 8]);
      GLOAD16(gB  + k0 + 32, &Bs[nxt][tid * 8]);
    }
    bf16x8 af[2], bfr[4];
    #pragma unroll
    for (int ms = 0; ms < 2; ms++)
      af[ms] = *(const bf16x8*)&As[cur][(arow + ms * 16) * 32 + swz];
    #pragma unroll
    for (int ns = 0; ns < 4; ns++)
      bfr[ns] = *(const bf16x8*)&Bs[cur][(ns * 16 + l16) * 32 + swz];
    #pragma unroll
    for (int ms = 0; ms < 2; ms++)
      #pragma unroll
      for (int ns = 0; ns < 4; ns++)
        acc[ms][ns] = __builtin_amdgcn_mfma_f32_16x16x32_bf16(bfr[ns], af[ms], acc[ms][ns], 0, 0, 0);
    __syncthreads();
    cur ^= 1;
  }

  #pragma unroll
  for (int ms = 0; ms < 2; ms++) {
    const long row = m0 + wave * 32 + ms * 16 + l16;
    #pragma unroll
    for (int ns = 0; ns < 4; ns++) {
      const int col = n0 + ns * 16 + quad * 4;
      const long idx = row * (long)N + col;
      float v[4];
      #pragma unroll
      for (int r = 0; r < 4; r++) v[r] = acc[ms][ns][r] + bf2f(bias[col + r]);
      if (EPI == 1) {
        #pragma unroll
        for (int r = 0; r < 4; r++)
          v[r] = 0.5f * v[r] * (1.0f + erff(v[r] * 0.70710678118654752f));
      }
      if (EPI == 2) {
        if (res_ext && xf32) {
          const float4 t = *(const float4*)((const float*)res + idx);
          v[0] += t.x; v[1] += t.y; v[2] += t.z; v[3] += t.w;
        } else {
          const bf16x4 t = *(const bf16x4*)((const bf16*)res + idx);
          #pragma unroll
          for (int r = 0; r < 4; r++) v[r] += (float)t[r];
        }
      }
      if (out_ext && xf32) {
        float4 t; t.x = v[0]; t.y = v[1]; t.z = v[2]; t.w = v[3];
        *(float4*)((float*)out + idx) = t;
      } else {
        bf16x4 t;
        #pragma unroll
        for (int r = 0; r < 4; r++) t[r] = (__bf16)v[r];
        *(bf16x4*)((bf16*)out + idx) = t;
      }
    }
  }
}

// ---------------- K=192 one-shot GEMM (+optional fused LN on A) -------------
// C = A[M,192] * BT[N,192]^T + bias (EPI as gemm_bt). K fits in LDS entirely:
// stage A panel (128x192, 48KB) + B panel (64x192, 24KB) ONCE, then one
// barrier and 48 straight MFMAs/wave. No mid-loop barriers, no re-staging.
// Swizzle (proven in mlp_fused/gemm_bt): slot' = (sl&24)|((sl^row)&7), 16B
// slots, involutive -> applied on global source for non-LN staging, and on
// the LDS rewrite for the LN path. Fragment reads land 2 lanes/bank (free).
// LN=1: A is raw xbuf; compute LayerNorm in-block (full 192-dim resident).
template <int EPI, int LN>
__global__ __launch_bounds__(256) void gemm_k192(const bf16* __restrict__ A,
                                                 const bf16* __restrict__ BT,
                                                 const bf16* __restrict__ bias,
                                                 const bf16* __restrict__ gN,
                                                 const bf16* __restrict__ bN,
                                                 const int* __restrict__ flagp,
                                                 const void* res, int res_ext,
                                                 void* out, int out_ext,
                                                 int M, int N) {
  __shared__ __align__(16) __bf16 Ash[128 * 192];  // 48 KB
  __shared__ __align__(16) __bf16 Bsh[64 * 192];   // 24 KB
  const int xf32 = (flagp[0] == 0);
  const int tid = threadIdx.x;
  const int wave = tid >> 6;
  const int lane = tid & 63;
  const int l16 = lane & 15;
  const int quad = lane >> 4;

  const int nbn = N >> 6;
  const int cpx = gridDim.x >> 3;
  const int wg = (gridDim.x & 7) ? (int)blockIdx.x
                                 : (blockIdx.x & 7) * cpx + (blockIdx.x >> 3);
  const int mb = wg / nbn;
  const int nb = wg - mb * nbn;
  const long m0 = (long)mb * 128;
  const int n0 = nb << 6;

  // ---- one-shot staging ----
  // B: always pre-swizzled source -> linear dest (64*24 = 1536 chunks, 6/thread)
  #pragma unroll
  for (int i = 0; i < 6; i++) {
    const int u = i * 256 + tid;
    const int r = u / 24, sl = u % 24;
    const int ssl = (sl & 24) | ((sl ^ r) & 7);
    GLOAD16(BT + (long)(n0 + r) * 192 + ssl * 8, &Bsh[u * 8]);
  }
  // A: 128*24 = 3072 chunks, 12/thread
  #pragma unroll
  for (int i = 0; i < 12; i++) {
    const int u = i * 256 + tid;
    const int r = u / 24, sl = u % 24;
    const int ssl = LN ? sl : ((sl & 24) | ((sl ^ r) & 7));  // LN: linear stage
    GLOAD16(A + (m0 + r) * (long)192 + ssl * 8, &Ash[u * 8]);
  }
  asm volatile("s_waitcnt vmcnt(0)" ::: "memory");
  __builtin_amdgcn_s_barrier();

  if (LN) {  // in-block LayerNorm over the resident 192-dim rows, rewrite swizzled
    const int row = tid >> 1, half = tid & 1;
    bf16x8 xr[12];
    #pragma unroll
    for (int i = 0; i < 12; i++)
      xr[i] = *(const bf16x8*)&Ash[row * 192 + (half * 12 + i) * 8];
    float s1 = 0.f;
    #pragma unroll
    for (int i = 0; i < 12; i++)
      #pragma unroll
      for (int j = 0; j < 8; j++) s1 += (float)xr[i][j];
    s1 += __shfl_xor(s1, 1, 64);
    const float mu = s1 * (1.0f / 192.0f);
    float s2 = 0.f;
    #pragma unroll
    for (int i = 0; i < 12; i++)
      #pragma unroll
      for (int j = 0; j < 8; j++) {
        const float d = (float)xr[i][j] - mu;
        s2 += d * d;
      }
    s2 += __shfl_xor(s2, 1, 64);
    const float rstd = rsqrtf(s2 * (1.0f / 192.0f) + 1e-5f);
    #pragma unroll
    for (int i = 0; i < 12; i++) {
      const int slot = half * 12 + i;
      const bf16x8 gg = *(const bf16x8*)&gN[slot * 8];
      const bf16x8 bb = *(const bf16x8*)&bN[slot * 8];
      bf16x8 nr;
      #pragma unroll
      for (int j = 0; j < 8; j++)
        nr[j] = (__bf16)(((float)xr[i][j] - mu) * rstd * (float)gg[j] + (float)bb[j]);
      xr[i] = nr;
    }
    __syncthreads();               // all raw reads done before permuted writes
    #pragma unroll
    for (int i = 0; i < 12; i++) {
      const int slot = half * 12 + i;
      const int sw = (slot & 24) | ((slot ^ row) & 7);
      *(bf16x8*)&Ash[row * 192 + sw * 8] = xr[i];
    }
    __syncthreads();
  }

  // ---- compute: 6 k-slices, no barriers ----
  floatx4 acc[2][4];
  #pragma unroll
  for (int i = 0; i < 2; i++)
    #pragma unroll
    for (int j = 0; j < 4; j++) acc[i][j] = (floatx4){0.f, 0.f, 0.f, 0.f};

  #pragma unroll
  for (int ks = 0; ks < 6; ks++) {
    const int sl = ks * 4 + quad;
    bf16x8 af[2], bfr[4];
    #pragma unroll
    for (int ms = 0; ms < 2; ms++) {
      const int r = wave * 32 + ms * 16 + l16;
      af[ms] = *(const bf16x8*)&Ash[r * 192 + ((sl & 24) | ((sl ^ r) & 7)) * 8];
    }
    #pragma unroll
    for (int ns = 0; ns < 4; ns++) {
      const int r = ns * 16 + l16;
      bfr[ns] = *(const bf16x8*)&Bsh[r * 192 + ((sl & 24) | ((sl ^ r) & 7)) * 8];
    }
    #pragma unroll
    for (int ms = 0; ms < 2; ms++)
      #pragma unroll
      for (int ns = 0; ns < 4; ns++)
        acc[ms][ns] = __builtin_amdgcn_mfma_f32_16x16x32_bf16(bfr[ns], af[ms], acc[ms][ns], 0, 0, 0);
  }

  // ---- epilogue (identical mapping to gemm_bt) ----
  #pragma unroll
  for (int ms = 0; ms < 2; ms++) {
    const long row = m0 + wave * 32 + ms * 16 + l16;
    #pragma unroll
    for (int ns = 0; ns < 4; ns++) {
      const int col = n0 + ns * 16 + quad * 4;
      const long idx = row * (long)N + col;
      float v[4];
      #pragma unroll
      for (int r = 0; r < 4; r++) v[r] = acc[ms][ns][r] + bf2f(bias[col + r]);
      if (EPI == 1) {
        #pragma unroll
        for (int r = 0; r < 4; r++)
          v[r] = 0.5f * v[r] * (1.0f + erff(v[r] * 0.70710678118654752f));
      }
      if (EPI == 2) {
        if (res_ext && xf32) {
          const float4 t = *(const float4*)((const float*)res + idx);
          v[0] += t.x; v[1] += t.y; v[2] += t.z; v[3] += t.w;
        } else {
          const bf16x4 t = *(const bf16x4*)((const bf16*)res + idx);
          #pragma unroll
          for (int r = 0; r < 4; r++) v[r] += (float)t[r];
        }
      }
      if (out_ext && xf32) {
        float4 t; t.x = v[0]; t.y = v[1]; t.z = v[2]; t.w = v[3];
        *(float4*)((float*)out + idx) = t;
      } else {
        bf16x4 t;
        #pragma unroll
        for (int r = 0; r < 4; r++) t[r] = (__bf16)v[r];
        *(bf16x4*)((bf16*)out + idx) = t;
      }
    }
  }
}

// ---------------- MFMA window attention: one wave per (window, head) --------
__global__ __launch_bounds__(64, 3) void attn_kernel(const bf16* __restrict__ qkv,  // [100352,576]
                                                     const bf16* __restrict__ btab, // [6,2450]
                                                     bf16* __restrict__ out) {      // [100352,192]
  __shared__ __align__(16) __bf16 vshT[32 * 64];  // V^T: [d][j], swizzled
  __shared__ __align__(16) __bf16 psh[64 * 64];   // P:   [i][j], swizzled
  __shared__ int rowIdx[64];
  __shared__ int regn[64];
  const int lane = threadIdx.x;
  const int q = lane >> 4, l16 = lane & 15;
  const int unit = blockIdx.x;          // [0, 12288)
  const int head = unit % 6;
  const int wIdx = unit / 6;            // [0, 2048)
  const int b = wIdx >> 8;
  const int w2 = wIdx & 255;
  const int wh = w2 >> 4;
  const int ww = w2 & 15;

  {
    const int l = lane < 49 ? lane : 48;
    const int r = l / 7, c = l - 7 * r;
    const int hr = wh * 7 + r;
    const int wr = ww * 7 + c;
    int h = hr + 3; if (h >= 112) h -= 112;
    int w = wr + 3; if (w >= 112) w -= 112;
    rowIdx[lane] = b * 12544 + h * 112 + w;
    const int rh = hr < 105 ? 0 : (hr < 109 ? 1 : 2);
    const int rw = wr < 105 ? 0 : (wr < 109 ? 1 : 2);
    regn[lane] = (lane < 49) ? rh * 3 + rw : 99;
  }
  __syncthreads();

  int ridx[4];
  #pragma unroll
  for (int t = 0; t < 4; t++) ridx[t] = rowIdx[t * 16 + l16];

  #pragma unroll
  for (int ii = 0; ii < 4; ii++) {
    const int i = lane + ii * 64;
    const int j = i >> 2, c = (i & 3) * 8;
    const bf16x8 vv = *(const bf16x8*)&qkv[(long)rowIdx[j] * 576 + 384 + head * 32 + c];
    #pragma unroll
    for (int jj = 0; jj < 8; jj++) {
      const int d = c + jj;
      vshT[d * 64 + (((j >> 3) ^ (d & 7)) << 3) + (j & 7)] = vv[jj];
    }
  }

  floatx4 s[4][4];
  #pragma unroll
  for (int it = 0; it < 4; it++)
    #pragma unroll
    for (int jt = 0; jt < 4; jt++) s[it][jt] = (floatx4){0.f, 0.f, 0.f, 0.f};
  {
    bf16x8 afq[4], bfk[4];
    #pragma unroll
    for (int t = 0; t < 4; t++) {
      const bf16* pQ = &qkv[(long)ridx[t] * 576 + head * 32 + q * 8];
      afq[t] = *(const bf16x8*)pQ;
      bfk[t] = *(const bf16x8*)(pQ + 192);
    }
    #pragma unroll
    for (int it = 0; it < 4; it++)
      #pragma unroll
      for (int jt = 0; jt < 4; jt++)
        s[it][jt] = __builtin_amdgcn_mfma_f32_16x16x32_bf16(afq[it], bfk[jt], s[it][jt], 0, 0, 0);
  }

  int regj[4];
  #pragma unroll
  for (int jt = 0; jt < 4; jt++) regj[jt] = regn[jt * 16 + l16];
  int regi[4][4];
  #pragma unroll
  for (int it = 0; it < 4; it++)
    #pragma unroll
    for (int r = 0; r < 4; r++) regi[it][r] = regn[it * 16 + q * 4 + r];

  const bf16* bt = btab + head * 2450;
  const float scale = 0.17677669529663687f;
  float mrow[4][4];
  #pragma unroll
  for (int it = 0; it < 4; it++)
    #pragma unroll
    for (int r = 0; r < 4; r++) mrow[it][r] = -3e38f;

  #pragma unroll
  for (int it = 0; it < 4; it++)
    #pragma unroll
    for (int jt = 0; jt < 4; jt++)
      #pragma unroll
      for (int r = 0; r < 4; r++) {
        const int i = it * 16 + q * 4 + r;
        const int j = jt * 16 + l16;
        const int bi = (i < 49 ? i : 48) * 50 + (j < 49 ? j : 48);
        float v = s[it][jt][r] * scale + bf2f(bt[bi]);
        if (regi[it][r] != regj[jt]) v -= 100.0f;
        v = (j < 49) ? v : -1e30f;
        s[it][jt][r] = v;
        mrow[it][r] = fmaxf(mrow[it][r], v);
      }
  #pragma unroll
  for (int it = 0; it < 4; it++)
    #pragma unroll
    for (int r = 0; r < 4; r++) {
      float m = mrow[it][r];
      #pragma unroll
      for (int off = 1; off < 16; off <<= 1) m = fmaxf(m, __shfl_xor(m, off, 64));
      mrow[it][r] = m;
    }
  float sum[4][4];
  #pragma unroll
  for (int it = 0; it < 4; it++)
    #pragma unroll
    for (int r = 0; r < 4; r++) sum[it][r] = 0.f;
  #pragma unroll
  for (int it = 0; it < 4; it++)
    #pragma unroll
    for (int jt = 0; jt < 4; jt++)
      #pragma unroll
      for (int r = 0; r < 4; r++) {
        const float e = __expf(s[it][jt][r] - mrow[it][r]);
        s[it][jt][r] = e;
        sum[it][r] += e;
      }
  #pragma unroll
  for (int it = 0; it < 4; it++)
    #pragma unroll
    for (int r = 0; r < 4; r++) {
      float t = sum[it][r];
      #pragma unroll
      for (int off = 1; off < 16; off <<= 1) t += __shfl_xor(t, off, 64);
      mrow[it][r] = 1.0f / t;
    }

  #pragma unroll
  for (int it = 0; it < 4; it++)
    #pragma unroll
    for (int jt = 0; jt < 4; jt++)
      #pragma unroll
      for (int r = 0; r < 4; r++) {
        const int i = it * 16 + q * 4 + r;
        const int j = jt * 16 + l16;
        psh[i * 64 + (((j >> 3) ^ (i & 7)) << 3) + (j & 7)] =
            (__bf16)(s[it][jt][r] * mrow[it][r]);
      }
  __syncthreads();

  floatx4 o[4][2];
  #pragma unroll
  for (int it = 0; it < 4; it++)
    #pragma unroll
    for (int dt = 0; dt < 2; dt++) o[it][dt] = (floatx4){0.f, 0.f, 0.f, 0.f};
  #pragma unroll
  for (int ks = 0; ks < 2; ks++) {
    bf16x8 av[2];
    #pragma unroll
    for (int dt = 0; dt < 2; dt++) {
      const int row = dt * 16 + l16;
      av[dt] = *(const bf16x8*)&vshT[row * 64 + (((ks * 4 + q) ^ (row & 7)) << 3)];
    }
    #pragma unroll
    for (int it = 0; it < 4; it++) {
      const int row = it * 16 + l16;
      const bf16x8 bp = *(const bf16x8*)&psh[row * 64 + (((ks * 4 + q) ^ (row & 7)) << 3)];
      #pragma unroll
      for (int dt = 0; dt < 2; dt++)
        o[it][dt] = __builtin_amdgcn_mfma_f32_16x16x32_bf16(bp, av[dt], o[it][dt], 0, 0, 0);
    }
  }

  #pragma unroll
  for (int it = 0; it < 4; it++)
    #pragma unroll
    for (int r = 0; r < 4; r++) {
      const int i = it * 16 + q * 4 + r;
      if (i < 49) {
        const long ob = (long)rowIdx[i] * 192 + head * 32;
        #pragma unroll
        for (int dt = 0; dt < 2; dt++)
          out[ob + dt * 16 + l16] = f2bf(o[it][dt][r]);
      }
    }
}

// ---------------------------------------------------------------------------
extern "C" void kernel_launch(void* const* d_in, const int* in_sizes, int n_in,
                              void* d_out, int out_size, void* d_ws, size_t ws_size,
                              hipStream_t stream) {
  const void* query   = d_in[0];
  const void* norm1_g = d_in[1];
  const void* norm1_b = d_in[2];
  const void* qkv_w   = d_in[3];
  const void* qkv_b   = d_in[4];
  const void* rpb     = d_in[5];
  const void* proj_w  = d_in[6];
  const void* proj_b  = d_in[7];
  const void* norm2_g = d_in[8];
  const void* norm2_b = d_in[9];
  const void* fc1_w   = d_in[10];
  const void* fc1_b   = d_in[11];
  const void* fc2_w   = d_in[12];
  const void* fc2_b   = d_in[13];

  const long M = 100352;

  int* flag  = (int*)d_ws;
  bf16* base = (bf16*)((char*)d_ws + 16);
  bf16* wsA   = base;                   // 19,267,584
  bf16* wsB   = wsA + M * 192;          // 77,070,336
  bf16* xbuf  = wsB + M * 768;          // 19,267,584
  bf16* qkvT  = xbuf + M * 192;         // 110,592
  bf16* projT = qkvT + 110592;          // 36,864
  bf16* fc1T  = projT + 36864;          // 147,456
  bf16* fc2T  = fc1T + 147456;          // 147,456
  bf16* pPAR  = fc2T + 147456;          // 3,510
  bf16* pQKVB = pPAR;                   // 576
  bf16* pPRJB = pQKVB + 576;            // 192
  bf16* pN1G  = pPRJB + 192;
  bf16* pN1B  = pN1G + 192;
  bf16* pN2G  = pN1B + 192;
  bf16* pN2B  = pN2G + 192;
  bf16* pFC1B = pN2B + 192;             // 768
  bf16* pFC2B = pFC1B + 768;            // 192
  bf16* pRPB  = pFC2B + 192;            // 1,014
  bf16* btab  = pPAR + 3510;            // 14,700

  detect_kernel<<<1, 64, 0, stream>>>((const unsigned int*)query, flag);
  cvt_params_kernel<<<14, 256, 0, stream>>>(flag, qkv_b, proj_b, norm1_g, norm1_b,
                                            norm2_g, norm2_b, fc1_b, fc2_b, rpb, pPAR);
  cvtT_kernel<<<(192 * 576 + 255) / 256, 256, 0, stream>>>(flag, qkv_w, qkvT, 192, 576);
  cvtT_kernel<<<(192 * 192 + 255) / 256, 256, 0, stream>>>(flag, proj_w, projT, 192, 192);
  cvtT_kernel<<<(192 * 768 + 255) / 256, 256, 0, stream>>>(flag, fc1_w, fc1T, 192, 768);
  cvtT_kernel<<<(768 * 192 + 255) / 256, 256, 0, stream>>>(flag, fc2_w, fc2T, 768, 192);
  biastab_kernel<<<(6 * 2450 + 255) / 256, 256, 0, stream>>>(pRPB, btab);

  // ---- attention branch ----
  ln_kernel<<<M / 4, 256, 0, stream>>>(flag, 1, query, pN1G, pN1B, wsA);
  // qkv: K=192 one-shot
  gemm_k192<0, 0><<<784 * 9, 256, 0, stream>>>(wsA, qkvT, pQKVB, nullptr, nullptr,
                                               flag, nullptr, 0, wsB, 0, (int)M, 576);
  attn_kernel<<<12288, 64, 0, stream>>>(wsB, btab, wsA);
  // proj: K=192 one-shot; x = query + attn @ proj_w + b -> xbuf
  gemm_k192<2, 0><<<784 * 3, 256, 0, stream>>>(wsA, projT, pPRJB, nullptr, nullptr,
                                               flag, query, 1, xbuf, 0, (int)M, 192);

  // ---- MLP branch ----
  // fc1 with fused LN2: h = GELU(LN2(xbuf) @ fc1 + b1) -> wsB   (no ln2 pass)
  gemm_k192<1, 1><<<784 * 12, 256, 0, stream>>>(xbuf, fc1T, pFC1B, pN2G, pN2B,
                                                flag, nullptr, 0, wsB, 0, (int)M, 768);
  // fc2: out = xbuf + h @ fc2 + b2 -> d_out (external dtype)
  gemm_bt<2><<<784 * 3, 256, 0, stream>>>(wsB, fc2T, pFC2B, flag,
                                          xbuf, 0, d_out, 1, (int)M, 192, 768);
}

// Round 10
// 590.977 us; speedup vs baseline: 1.5101x; 1.0445x over previous
//
#include <hip/hip_runtime.h>
#include <hip/hip_bf16.h>
#include <math.h>

using bf16 = __hip_bfloat16;
typedef __bf16 bf16x8 __attribute__((ext_vector_type(8)));
typedef __bf16 bf16x4 __attribute__((ext_vector_type(4)));
typedef float floatx4 __attribute__((ext_vector_type(4)));

__device__ __forceinline__ float bf2f(bf16 x) { return __bfloat162float(x); }
__device__ __forceinline__ bf16 f2bf(float x) { return __float2bfloat16(x); }

// flag semantics: flagp[0] == 1 -> external tensors are bf16; 0 -> float32.
__device__ __forceinline__ float loadExt(const void* p, long i, int f32) {
  return f32 ? ((const float*)p)[i] : bf2f(((const bf16*)p)[i]);
}
__device__ __forceinline__ void storeExt(void* p, long i, int f32, float v) {
  if (f32) ((float*)p)[i] = v;
  else     ((bf16*)p)[i] = f2bf(v);
}

// tanh-approx GELU: max |err| vs exact ~3e-4, far below bf16 quantization.
__device__ __forceinline__ float gelu_tanh(float v) {
  const float u = 0.7978845608028654f * v * (1.0f + 0.044715f * v * v);
  const float a = fabsf(u);
  const float e = __expf(-2.0f * a);
  float t = (1.0f - e) / (1.0f + e);
  t = (u < 0.f) ? -t : t;
  return 0.5f * v * (1.0f + t);
}

// async 16B global->LDS copy (gfx950). LDS dest is wave-uniform base + lane*16.
#define GLOAD16(gp, lp)                                                       \
  __builtin_amdgcn_global_load_lds(                                           \
      (const __attribute__((address_space(1))) void*)(gp),                    \
      (__attribute__((address_space(3))) void*)(lp), 16, 0, 0)

// ---------------- dtype detector: 1 wave, inspects low 16 bits of 64 words ---
__global__ void detect_kernel(const unsigned int* __restrict__ q, int* __restrict__ flag) {
  const int lane = threadIdx.x;
  const unsigned int w = q[lane];
  const unsigned int lo = w & 0xffffu;
  const unsigned int e = (lo >> 7) & 0xffu;
  const bool ok = (lo == 0u) || (e >= 100u && e <= 141u);
  const unsigned long long m = __ballot(ok);
  if (lane == 0) flag[0] = (__popcll(m) == 64) ? 1 : 0;
}

// ---------------- merged convert: 4 weight transposes + 9 param tensors -----
// region layout (element index i):
//   [0,110592)        qkvT [576][192]  <- qkv_w [192][576]
//   [..,+36864)       projT[192][192]  <- proj_w[192][192]
//   [..,+147456)      fc1T [768][192]  <- fc1_w [192][768]
//   [..,+147456)      fc2T [192][768]  <- fc2_w [768][192]
//   [..,+3510)        pPAR (bias/LN/rpb chain, same order as before)
__global__ void cvt_all_kernel(const int* __restrict__ flagp,
                               const void* qkv_w, const void* proj_w,
                               const void* fc1_w, const void* fc2_w,
                               const void* qkv_b, const void* proj_b,
                               const void* n1g, const void* n1b,
                               const void* n2g, const void* n2b,
                               const void* fc1_b, const void* fc2_b,
                               const void* rpb,
                               bf16* __restrict__ qkvT, bf16* __restrict__ projT,
                               bf16* __restrict__ fc1T, bf16* __restrict__ fc2T,
                               bf16* __restrict__ pPAR) {
  const int f32 = (flagp[0] == 0);
  int i = blockIdx.x * blockDim.x + threadIdx.x;
  if (i < 110592) {
    const int n = i / 192, k = i - n * 192;
    qkvT[i] = f2bf(loadExt(qkv_w, (long)k * 576 + n, f32));
    return;
  }
  i -= 110592;
  if (i < 36864) {
    const int n = i / 192, k = i - n * 192;
    projT[i] = f2bf(loadExt(proj_w, (long)k * 192 + n, f32));
    return;
  }
  i -= 36864;
  if (i < 147456) {
    const int n = i / 192, k = i - n * 192;
    fc1T[i] = f2bf(loadExt(fc1_w, (long)k * 768 + n, f32));
    return;
  }
  i -= 147456;
  if (i < 147456) {
    const int n = i / 768, k = i - n * 768;
    fc2T[i] = f2bf(loadExt(fc2_w, (long)k * 192 + n, f32));
    return;
  }
  i -= 147456;
  if (i >= 3510) return;
  const void* src; int j = i;
  if      (j < 576)  { src = qkv_b; }
  else if ((j -= 576)  < 192) { src = proj_b; }
  else if ((j -= 192)  < 192) { src = n1g; }
  else if ((j -= 192)  < 192) { src = n1b; }
  else if ((j -= 192)  < 192) { src = n2g; }
  else if ((j -= 192)  < 192) { src = n2b; }
  else if ((j -= 192)  < 768) { src = fc1_b; }
  else if ((j -= 768)  < 192) { src = fc2_b; }
  else { j -= 192; src = rpb; }
  pPAR[i] = f2bf(loadExt(src, j, f32));
}

// ---------------- rel-pos bias table: btab[head][n*50+m] (padded stride 50) --
__global__ void biastab_kernel(const bf16* __restrict__ rpb,
                               bf16* __restrict__ btab) {
  int i = blockIdx.x * blockDim.x + threadIdx.x;
  if (i >= 6 * 2450) return;
  int head = i / 2450, r = i - head * 2450;
  int n = r / 50, m = r - n * 50;
  float v = 0.f;
  if (n < 49 && m < 49) {
    int r1 = n / 7, c1 = n - 7 * r1, r2 = m / 7, c2 = m - 7 * r2;
    v = bf2f(rpb[((r1 - r2 + 6) * 13 + (c1 - c2 + 6)) * 6 + head]);
  }
  btab[i] = f2bf(v);
}

// ---------------- LayerNorm: one wave per 192-elem row --------------------
__global__ __launch_bounds__(256) void ln_kernel(const int* __restrict__ flagp, int ext,
                                                 const void* __restrict__ x,
                                                 const bf16* __restrict__ g,
                                                 const bf16* __restrict__ b,
                                                 bf16* __restrict__ out) {
  const int f32 = ext && (flagp[0] == 0);
  const long row = (long)blockIdx.x * 4 + (threadIdx.x >> 6);
  const int lane = threadIdx.x & 63;
  const long gbase = row * 192;
  float v0 = loadExt(x, gbase + lane, f32);
  float v1 = loadExt(x, gbase + lane + 64, f32);
  float v2 = loadExt(x, gbase + lane + 128, f32);
  float s = v0 + v1 + v2;
  #pragma unroll
  for (int off = 32; off > 0; off >>= 1) s += __shfl_xor(s, off, 64);
  const float mu = s * (1.0f / 192.0f);
  float d0 = v0 - mu, d1 = v1 - mu, d2 = v2 - mu;
  float vv = d0 * d0 + d1 * d1 + d2 * d2;
  #pragma unroll
  for (int off = 32; off > 0; off >>= 1) vv += __shfl_xor(vv, off, 64);
  const float rstd = rsqrtf(vv * (1.0f / 192.0f) + 1e-5f);
  bf16* orow = out + row * 192;
  orow[lane]       = f2bf(d0 * rstd * bf2f(g[lane])       + bf2f(b[lane]));
  orow[lane + 64]  = f2bf(d1 * rstd * bf2f(g[lane + 64])  + bf2f(b[lane + 64]));
  orow[lane + 128] = f2bf(d2 * rstd * bf2f(g[lane + 128]) + bf2f(b[lane + 128]));
}

// ---------------- bf16 MFMA GEMM (round-4 proven): 2-buffer prefetch --------
// EPI: 0 = bias, 1 = bias+GELU, 2 = bias+residual.  (used for fc2, K=768)
template <int EPI>
__global__ __launch_bounds__(256) void gemm_bt(const bf16* __restrict__ A,
                                               const bf16* __restrict__ BT,
                                               const bf16* __restrict__ bias,
                                               const int* __restrict__ flagp,
                                               const void* res, int res_ext,
                                               void* out, int out_ext,
                                               int M, int N, int K) {
  __shared__ __align__(16) bf16 As[2][128 * 32];
  __shared__ __align__(16) bf16 Bs[2][64 * 32];
  const int xf32 = (flagp[0] == 0);
  const int tid = threadIdx.x;
  const int wave = tid >> 6;
  const int lane = tid & 63;
  const int l16 = lane & 15;
  const int quad = lane >> 4;

  const int nbn = N >> 6;
  const int cpx = gridDim.x >> 3;
  const int wg = (gridDim.x & 7) ? (int)blockIdx.x
                                 : (blockIdx.x & 7) * cpx + (blockIdx.x >> 3);
  const int mb = wg / nbn;
  const int nb = wg - mb * nbn;
  const long m0 = (long)mb * 128;
  const int n0 = nb << 6;

  const int rS = tid >> 2;
  const int sS = tid & 3;
  const int ss = sS ^ ((rS >> 1) & 3);
  const bf16* gA0 = A + (m0 + rS) * (long)K + ss * 8;
  const bf16* gA1 = A + (m0 + rS + 64) * (long)K + ss * 8;
  const bf16* gB  = BT + (long)(n0 + rS) * K + ss * 8;

  floatx4 acc[2][4];
  #pragma unroll
  for (int i = 0; i < 2; i++)
    #pragma unroll
    for (int j = 0; j < 4; j++) acc[i][j] = (floatx4){0.f, 0.f, 0.f, 0.f};

  const int swz = (quad ^ ((l16 >> 1) & 3)) << 3;
  const int arow = wave * 32 + l16;

  GLOAD16(gA0, &As[0][tid * 8]);
  GLOAD16(gA1, &As[0][(tid + 256) * 8]);
  GLOAD16(gB,  &Bs[0][tid * 8]);
  __syncthreads();

  int cur = 0;
  for (int k0 = 0; k0 < K; k0 += 32) {
    if (k0 + 32 < K) {
      const int nxt = cur ^ 1;
      GLOAD16(gA0 + k0 + 32, &As[nxt][tid * 8]);
      GLOAD16(gA1 + k0 + 32, &As[nxt][(tid + 256) * 8]);
      GLOAD16(gB  + k0 + 32, &Bs[nxt][tid * 8]);
    }
    bf16x8 af[2], bfr[4];
    #pragma unroll
    for (int ms = 0; ms < 2; ms++)
      af[ms] = *(const bf16x8*)&As[cur][(arow + ms * 16) * 32 + swz];
    #pragma unroll
    for (int ns = 0; ns < 4; ns++)
      bfr[ns] = *(const bf16x8*)&Bs[cur][(ns * 16 + l16) * 32 + swz];
    #pragma unroll
    for (int ms = 0; ms < 2; ms++)
      #pragma unroll
      for (int ns = 0; ns < 4; ns++)
        acc[ms][ns] = __builtin_amdgcn_mfma_f32_16x16x32_bf16(bfr[ns], af[ms], acc[ms][ns], 0, 0, 0);
    __syncthreads();
    cur ^= 1;
  }

  #pragma unroll
  for (int ms = 0; ms < 2; ms++) {
    const long row = m0 + wave * 32 + ms * 16 + l16;
    #pragma unroll
    for (int ns = 0; ns < 4; ns++) {
      const int col = n0 + ns * 16 + quad * 4;
      const long idx = row * (long)N + col;
      float v[4];
      #pragma unroll
      for (int r = 0; r < 4; r++) v[r] = acc[ms][ns][r] + bf2f(bias[col + r]);
      if (EPI == 1) {
        #pragma unroll
        for (int r = 0; r < 4; r++) v[r] = gelu_tanh(v[r]);
      }
      if (EPI == 2) {
        if (res_ext && xf32) {
          const float4 t = *(const float4*)((const float*)res + idx);
          v[0] += t.x; v[1] += t.y; v[2] += t.z; v[3] += t.w;
        } else {
          const bf16x4 t = *(const bf16x4*)((const bf16*)res + idx);
          #pragma unroll
          for (int r = 0; r < 4; r++) v[r] += (float)t[r];
        }
      }
      if (out_ext && xf32) {
        float4 t; t.x = v[0]; t.y = v[1]; t.z = v[2]; t.w = v[3];
        *(float4*)((float*)out + idx) = t;
      } else {
        bf16x4 t;
        #pragma unroll
        for (int r = 0; r < 4; r++) t[r] = (__bf16)v[r];
        *(bf16x4*)((bf16*)out + idx) = t;
      }
    }
  }
}

// ---------------- K=192 one-shot GEMM (no LN; staging pre-swizzled) ---------
// C = A[M,192] * BT[N,192]^T + bias. Stage A panel (128x192, 48KB) + B panel
// (64x192, 24KB) ONCE, one barrier, 48 straight MFMAs/wave. No mid-loop
// barriers. Fragment reads 2 lanes/bank (free).
template <int EPI>
__global__ __launch_bounds__(256) void gemm_k192(const bf16* __restrict__ A,
                                                 const bf16* __restrict__ BT,
                                                 const bf16* __restrict__ bias,
                                                 const int* __restrict__ flagp,
                                                 const void* res, int res_ext,
                                                 void* out, int out_ext,
                                                 int M, int N) {
  __shared__ __align__(16) __bf16 Ash[128 * 192];  // 48 KB
  __shared__ __align__(16) __bf16 Bsh[64 * 192];   // 24 KB
  const int xf32 = (flagp[0] == 0);
  const int tid = threadIdx.x;
  const int wave = tid >> 6;
  const int lane = tid & 63;
  const int l16 = lane & 15;
  const int quad = lane >> 4;

  const int nbn = N >> 6;
  const int cpx = gridDim.x >> 3;
  const int wg = (gridDim.x & 7) ? (int)blockIdx.x
                                 : (blockIdx.x & 7) * cpx + (blockIdx.x >> 3);
  const int mb = wg / nbn;
  const int nb = wg - mb * nbn;
  const long m0 = (long)mb * 128;
  const int n0 = nb << 6;

  // ---- one-shot staging, pre-swizzled source -> linear dest ----
  #pragma unroll
  for (int i = 0; i < 6; i++) {
    const int u = i * 256 + tid;
    const int r = u / 24, sl = u % 24;
    const int ssl = (sl & 24) | ((sl ^ r) & 7);
    GLOAD16(BT + (long)(n0 + r) * 192 + ssl * 8, &Bsh[u * 8]);
  }
  #pragma unroll
  for (int i = 0; i < 12; i++) {
    const int u = i * 256 + tid;
    const int r = u / 24, sl = u % 24;
    const int ssl = (sl & 24) | ((sl ^ r) & 7);
    GLOAD16(A + (m0 + r) * (long)192 + ssl * 8, &Ash[u * 8]);
  }
  asm volatile("s_waitcnt vmcnt(0)" ::: "memory");
  __builtin_amdgcn_s_barrier();

  // ---- compute: 6 k-slices, no barriers ----
  floatx4 acc[2][4];
  #pragma unroll
  for (int i = 0; i < 2; i++)
    #pragma unroll
    for (int j = 0; j < 4; j++) acc[i][j] = (floatx4){0.f, 0.f, 0.f, 0.f};

  #pragma unroll
  for (int ks = 0; ks < 6; ks++) {
    const int sl = ks * 4 + quad;
    bf16x8 af[2], bfr[4];
    #pragma unroll
    for (int ms = 0; ms < 2; ms++) {
      const int r = wave * 32 + ms * 16 + l16;
      af[ms] = *(const bf16x8*)&Ash[r * 192 + ((sl & 24) | ((sl ^ r) & 7)) * 8];
    }
    #pragma unroll
    for (int ns = 0; ns < 4; ns++) {
      const int r = ns * 16 + l16;
      bfr[ns] = *(const bf16x8*)&Bsh[r * 192 + ((sl & 24) | ((sl ^ r) & 7)) * 8];
    }
    #pragma unroll
    for (int ms = 0; ms < 2; ms++)
      #pragma unroll
      for (int ns = 0; ns < 4; ns++)
        acc[ms][ns] = __builtin_amdgcn_mfma_f32_16x16x32_bf16(bfr[ns], af[ms], acc[ms][ns], 0, 0, 0);
  }

  // ---- epilogue ----
  #pragma unroll
  for (int ms = 0; ms < 2; ms++) {
    const long row = m0 + wave * 32 + ms * 16 + l16;
    #pragma unroll
    for (int ns = 0; ns < 4; ns++) {
      const int col = n0 + ns * 16 + quad * 4;
      const long idx = row * (long)N + col;
      float v[4];
      #pragma unroll
      for (int r = 0; r < 4; r++) v[r] = acc[ms][ns][r] + bf2f(bias[col + r]);
      if (EPI == 1) {
        #pragma unroll
        for (int r = 0; r < 4; r++) v[r] = gelu_tanh(v[r]);
      }
      if (EPI == 2) {
        if (res_ext && xf32) {
          const float4 t = *(const float4*)((const float*)res + idx);
          v[0] += t.x; v[1] += t.y; v[2] += t.z; v[3] += t.w;
        } else {
          const bf16x4 t = *(const bf16x4*)((const bf16*)res + idx);
          #pragma unroll
          for (int r = 0; r < 4; r++) v[r] += (float)t[r];
        }
      }
      if (out_ext && xf32) {
        float4 t; t.x = v[0]; t.y = v[1]; t.z = v[2]; t.w = v[3];
        *(float4*)((float*)out + idx) = t;
      } else {
        bf16x4 t;
        #pragma unroll
        for (int r = 0; r < 4; r++) t[r] = (__bf16)v[r];
        *(bf16x4*)((bf16*)out + idx) = t;
      }
    }
  }
}

// ---------------- MFMA window attention: one wave per (window, head) --------
__global__ __launch_bounds__(64, 3) void attn_kernel(const bf16* __restrict__ qkv,  // [100352,576]
                                                     const bf16* __restrict__ btab, // [6,2450]
                                                     bf16* __restrict__ out) {      // [100352,192]
  __shared__ __align__(16) __bf16 vshT[32 * 64];  // V^T: [d][j], swizzled
  __shared__ __align__(16) __bf16 psh[64 * 64];   // P:   [i][j], swizzled
  __shared__ int rowIdx[64];
  __shared__ int regn[64];
  const int lane = threadIdx.x;
  const int q = lane >> 4, l16 = lane & 15;
  const int unit = blockIdx.x;          // [0, 12288)
  const int head = unit % 6;
  const int wIdx = unit / 6;            // [0, 2048)
  const int b = wIdx >> 8;
  const int w2 = wIdx & 255;
  const int wh = w2 >> 4;
  const int ww = w2 & 15;

  {
    const int l = lane < 49 ? lane : 48;
    const int r = l / 7, c = l - 7 * r;
    const int hr = wh * 7 + r;
    const int wr = ww * 7 + c;
    int h = hr + 3; if (h >= 112) h -= 112;
    int w = wr + 3; if (w >= 112) w -= 112;
    rowIdx[lane] = b * 12544 + h * 112 + w;
    const int rh = hr < 105 ? 0 : (hr < 109 ? 1 : 2);
    const int rw = wr < 105 ? 0 : (wr < 109 ? 1 : 2);
    regn[lane] = (lane < 49) ? rh * 3 + rw : 99;
  }
  __syncthreads();

  int ridx[4];
  #pragma unroll
  for (int t = 0; t < 4; t++) ridx[t] = rowIdx[t * 16 + l16];

  #pragma unroll
  for (int ii = 0; ii < 4; ii++) {
    const int i = lane + ii * 64;
    const int j = i >> 2, c = (i & 3) * 8;
    const bf16x8 vv = *(const bf16x8*)&qkv[(long)rowIdx[j] * 576 + 384 + head * 32 + c];
    #pragma unroll
    for (int jj = 0; jj < 8; jj++) {
      const int d = c + jj;
      vshT[d * 64 + (((j >> 3) ^ (d & 7)) << 3) + (j & 7)] = vv[jj];
    }
  }

  floatx4 s[4][4];
  #pragma unroll
  for (int it = 0; it < 4; it++)
    #pragma unroll
    for (int jt = 0; jt < 4; jt++) s[it][jt] = (floatx4){0.f, 0.f, 0.f, 0.f};
  {
    bf16x8 afq[4], bfk[4];
    #pragma unroll
    for (int t = 0; t < 4; t++) {
      const bf16* pQ = &qkv[(long)ridx[t] * 576 + head * 32 + q * 8];
      afq[t] = *(const bf16x8*)pQ;
      bfk[t] = *(const bf16x8*)(pQ + 192);
    }
    #pragma unroll
    for (int it = 0; it < 4; it++)
      #pragma unroll
      for (int jt = 0; jt < 4; jt++)
        s[it][jt] = __builtin_amdgcn_mfma_f32_16x16x32_bf16(afq[it], bfk[jt], s[it][jt], 0, 0, 0);
  }

  int regj[4];
  #pragma unroll
  for (int jt = 0; jt < 4; jt++) regj[jt] = regn[jt * 16 + l16];
  int regi[4][4];
  #pragma unroll
  for (int it = 0; it < 4; it++)
    #pragma unroll
    for (int r = 0; r < 4; r++) regi[it][r] = regn[it * 16 + q * 4 + r];

  const bf16* bt = btab + head * 2450;
  const float scale = 0.17677669529663687f;
  float mrow[4][4];
  #pragma unroll
  for (int it = 0; it < 4; it++)
    #pragma unroll
    for (int r = 0; r < 4; r++) mrow[it][r] = -3e38f;

  #pragma unroll
  for (int it = 0; it < 4; it++)
    #pragma unroll
    for (int jt = 0; jt < 4; jt++)
      #pragma unroll
      for (int r = 0; r < 4; r++) {
        const int i = it * 16 + q * 4 + r;
        const int j = jt * 16 + l16;
        const int bi = (i < 49 ? i : 48) * 50 + (j < 49 ? j : 48);
        float v = s[it][jt][r] * scale + bf2f(bt[bi]);
        if (regi[it][r] != regj[jt]) v -= 100.0f;
        v = (j < 49) ? v : -1e30f;
        s[it][jt][r] = v;
        mrow[it][r] = fmaxf(mrow[it][r], v);
      }
  #pragma unroll
  for (int it = 0; it < 4; it++)
    #pragma unroll
    for (int r = 0; r < 4; r++) {
      float m = mrow[it][r];
      #pragma unroll
      for (int off = 1; off < 16; off <<= 1) m = fmaxf(m, __shfl_xor(m, off, 64));
      mrow[it][r] = m;
    }
  float sum[4][4];
  #pragma unroll
  for (int it = 0; it < 4; it++)
    #pragma unroll
    for (int r = 0; r < 4; r++) sum[it][r] = 0.f;
  #pragma unroll
  for (int it = 0; it < 4; it++)
    #pragma unroll
    for (int jt = 0; jt < 4; jt++)
      #pragma unroll
      for (int r = 0; r < 4; r++) {
        const float e = __expf(s[it][jt][r] - mrow[it][r]);
        s[it][jt][r] = e;
        sum[it][r] += e;
      }
  #pragma unroll
  for (int it = 0; it < 4; it++)
    #pragma unroll
    for (int r = 0; r < 4; r++) {
      float t = sum[it][r];
      #pragma unroll
      for (int off = 1; off < 16; off <<= 1) t += __shfl_xor(t, off, 64);
      mrow[it][r] = 1.0f / t;
    }

  #pragma unroll
  for (int it = 0; it < 4; it++)
    #pragma unroll
    for (int jt = 0; jt < 4; jt++)
      #pragma unroll
      for (int r = 0; r < 4; r++) {
        const int i = it * 16 + q * 4 + r;
        const int j = jt * 16 + l16;
        psh[i * 64 + (((j >> 3) ^ (i & 7)) << 3) + (j & 7)] =
            (__bf16)(s[it][jt][r] * mrow[it][r]);
      }
  __syncthreads();

  floatx4 o[4][2];
  #pragma unroll
  for (int it = 0; it < 4; it++)
    #pragma unroll
    for (int dt = 0; dt < 2; dt++) o[it][dt] = (floatx4){0.f, 0.f, 0.f, 0.f};
  #pragma unroll
  for (int ks = 0; ks < 2; ks++) {
    bf16x8 av[2];
    #pragma unroll
    for (int dt = 0; dt < 2; dt++) {
      const int row = dt * 16 + l16;
      av[dt] = *(const bf16x8*)&vshT[row * 64 + (((ks * 4 + q) ^ (row & 7)) << 3)];
    }
    #pragma unroll
    for (int it = 0; it < 4; it++) {
      const int row = it * 16 + l16;
      const bf16x8 bp = *(const bf16x8*)&psh[row * 64 + (((ks * 4 + q) ^ (row & 7)) << 3)];
      #pragma unroll
      for (int dt = 0; dt < 2; dt++)
        o[it][dt] = __builtin_amdgcn_mfma_f32_16x16x32_bf16(bp, av[dt], o[it][dt], 0, 0, 0);
    }
  }

  #pragma unroll
  for (int it = 0; it < 4; it++)
    #pragma unroll
    for (int r = 0; r < 4; r++) {
      const int i = it * 16 + q * 4 + r;
      if (i < 49) {
        const long ob = (long)rowIdx[i] * 192 + head * 32;
        #pragma unroll
        for (int dt = 0; dt < 2; dt++)
          out[ob + dt * 16 + l16] = f2bf(o[it][dt][r]);
      }
    }
}

// ---------------------------------------------------------------------------
extern "C" void kernel_launch(void* const* d_in, const int* in_sizes, int n_in,
                              void* d_out, int out_size, void* d_ws, size_t ws_size,
                              hipStream_t stream) {
  const void* query   = d_in[0];
  const void* norm1_g = d_in[1];
  const void* norm1_b = d_in[2];
  const void* qkv_w   = d_in[3];
  const void* qkv_b   = d_in[4];
  const void* rpb     = d_in[5];
  const void* proj_w  = d_in[6];
  const void* proj_b  = d_in[7];
  const void* norm2_g = d_in[8];
  const void* norm2_b = d_in[9];
  const void* fc1_w   = d_in[10];
  const void* fc1_b   = d_in[11];
  const void* fc2_w   = d_in[12];
  const void* fc2_b   = d_in[13];

  const long M = 100352;

  int* flag  = (int*)d_ws;
  bf16* base = (bf16*)((char*)d_ws + 16);
  bf16* wsA   = base;                   // 19,267,584
  bf16* wsB   = wsA + M * 192;          // 77,070,336
  bf16* xbuf  = wsB + M * 768;          // 19,267,584
  bf16* qkvT  = xbuf + M * 192;         // 110,592
  bf16* projT = qkvT + 110592;          // 36,864
  bf16* fc1T  = projT + 36864;          // 147,456
  bf16* fc2T  = fc1T + 147456;          // 147,456
  bf16* pPAR  = fc2T + 147456;          // 3,510
  bf16* pQKVB = pPAR;                   // 576
  bf16* pPRJB = pQKVB + 576;            // 192
  bf16* pN1G  = pPRJB + 192;
  bf16* pN1B  = pN1G + 192;
  bf16* pN2G  = pN1B + 192;
  bf16* pN2B  = pN2G + 192;
  bf16* pFC1B = pN2B + 192;             // 768
  bf16* pFC2B = pFC1B + 768;            // 192
  bf16* pRPB  = pFC2B + 192;            // 1,014
  bf16* btab  = pPAR + 3510;            // 14,700

  detect_kernel<<<1, 64, 0, stream>>>((const unsigned int*)query, flag);
  cvt_all_kernel<<<(445878 + 255) / 256, 256, 0, stream>>>(
      flag, qkv_w, proj_w, fc1_w, fc2_w, qkv_b, proj_b, norm1_g, norm1_b,
      norm2_g, norm2_b, fc1_b, fc2_b, rpb, qkvT, projT, fc1T, fc2T, pPAR);
  biastab_kernel<<<(6 * 2450 + 255) / 256, 256, 0, stream>>>(pRPB, btab);

  // ---- attention branch ----
  ln_kernel<<<M / 4, 256, 0, stream>>>(flag, 1, query, pN1G, pN1B, wsA);
  // qkv: K=192 one-shot
  gemm_k192<0><<<784 * 9, 256, 0, stream>>>(wsA, qkvT, pQKVB, flag,
                                            nullptr, 0, wsB, 0, (int)M, 576);
  attn_kernel<<<12288, 64, 0, stream>>>(wsB, btab, wsA);
  // proj: K=192 one-shot; x = query + attn @ proj_w + b -> xbuf
  gemm_k192<2><<<784 * 3, 256, 0, stream>>>(wsA, projT, pPRJB, flag,
                                            query, 1, xbuf, 0, (int)M, 192);

  // ---- MLP branch ----
  ln_kernel<<<M / 4, 256, 0, stream>>>(flag, 0, xbuf, pN2G, pN2B, wsA);
  // fc1: h = GELU(ln2 @ fc1 + b1) -> wsB
  gemm_k192<1><<<784 * 12, 256, 0, stream>>>(wsA, fc1T, pFC1B, flag,
                                             nullptr, 0, wsB, 0, (int)M, 768);
  // fc2: out = xbuf + h @ fc2 + b2 -> d_out (external dtype)
  gemm_bt<2><<<784 * 3, 256, 0, stream>>>(wsB, fc2T, pFC2B, flag,
                                          xbuf, 0, d_out, 1, (int)M, 192, 768);
}